// Round 3
// baseline (363.581 us; speedup 1.0000x reference)
//
#include <hip/hip_runtime.h>
#include <math.h>

#define DD 2048
#define EE 64
#define KQ 32
#define TOKTILE 256

// ---------------- K0: zero the histogram ----------------
__global__ __launch_bounds__(64) void sr_zero(int* __restrict__ counts) {
  counts[threadIdx.x] = 0;
}

// ---------------- K1: gate GEMM, K-split partials ----------------
// logits[t][e] = sum_d x[t,d] * wg[e,d]; block = 256 tokens x 64 experts x Kblk.
// Thread tile 8 tokens x 8 experts; LDS staged transposed: xs[k][t], wsh[k][e].
__global__ __launch_bounds__(256, 2) void sr_gemm(
    const float* __restrict__ x, const float* __restrict__ wg,
    float* __restrict__ partial, int N, int ksplit)
{
  __shared__ float xs[KQ][TOKTILE];  // 32 KB
  __shared__ float wsh[KQ][EE];      // 8 KB
  const int ntiles = N / TOKTILE;
  const int tt = blockIdx.x % ntiles;
  const int kc = blockIdx.x / ntiles;
  const int kblk = DD / ksplit;
  const int nchunk = kblk / KQ;
  const int k0 = kc * kblk;
  const int t0 = tt * TOKTILE;
  const int tid = threadIdx.x;
  const int ti = tid & 31;   // token thread 0..31 -> tokens 4ti & 128+4ti
  const int tj = tid >> 5;   // expert thread 0..7 -> experts 4tj & 32+4tj

  float acc[8][8];
#pragma unroll
  for (int r = 0; r < 8; ++r)
#pragma unroll
    for (int c = 0; c < 8; ++c) acc[r][c] = 0.f;

  for (int ch = 0; ch < nchunk; ++ch) {
    const int kb = k0 + ch * KQ;
    // stage x chunk (256 tok x 32 k), transposed
#pragma unroll
    for (int p = 0; p < 8; ++p) {
      const int row = p * 32 + (tid >> 3);
      const int c4 = (tid & 7) * 4;
      const float4 v = *reinterpret_cast<const float4*>(
          &x[(size_t)(t0 + row) * DD + kb + c4]);
      xs[c4 + 0][row] = v.x;
      xs[c4 + 1][row] = v.y;
      xs[c4 + 2][row] = v.z;
      xs[c4 + 3][row] = v.w;
    }
    // stage w chunk (64 e x 32 k), transposed
    {
      const int e = tid >> 2;
      const int kq = (tid & 3) * 8;
      const float4 a = *reinterpret_cast<const float4*>(&wg[(size_t)e * DD + kb + kq]);
      const float4 b = *reinterpret_cast<const float4*>(&wg[(size_t)e * DD + kb + kq + 4]);
      wsh[kq + 0][e] = a.x; wsh[kq + 1][e] = a.y; wsh[kq + 2][e] = a.z; wsh[kq + 3][e] = a.w;
      wsh[kq + 4][e] = b.x; wsh[kq + 5][e] = b.y; wsh[kq + 6][e] = b.z; wsh[kq + 7][e] = b.w;
    }
    __syncthreads();
#pragma unroll 8
    for (int k = 0; k < KQ; ++k) {
      float xv[8], wv[8];
      *reinterpret_cast<float4*>(&xv[0]) = *reinterpret_cast<const float4*>(&xs[k][4 * ti]);
      *reinterpret_cast<float4*>(&xv[4]) = *reinterpret_cast<const float4*>(&xs[k][128 + 4 * ti]);
      *reinterpret_cast<float4*>(&wv[0]) = *reinterpret_cast<const float4*>(&wsh[k][4 * tj]);
      *reinterpret_cast<float4*>(&wv[4]) = *reinterpret_cast<const float4*>(&wsh[k][32 + 4 * tj]);
#pragma unroll
      for (int r = 0; r < 8; ++r)
#pragma unroll
        for (int c = 0; c < 8; ++c) acc[r][c] = fmaf(xv[r], wv[c], acc[r][c]);
    }
    __syncthreads();
  }
  // partial[kc][e][t], coalesced float4 over tokens
#pragma unroll
  for (int c = 0; c < 8; ++c) {
    const int e = (c < 4) ? (4 * tj + c) : (32 + 4 * tj + (c - 4));
#pragma unroll
    for (int h = 0; h < 2; ++h) {
      const int tb = t0 + h * 128 + 4 * ti;
      float4 v = make_float4(acc[h * 4 + 0][c], acc[h * 4 + 1][c],
                             acc[h * 4 + 2][c], acc[h * 4 + 3][c]);
      *reinterpret_cast<float4*>(&partial[((size_t)kc * EE + e) * N + tb]) = v;
    }
  }
}

// ---------------- K1b: per-token epilogue ----------------
__global__ __launch_bounds__(64) void sr_epilogue(
    const float* __restrict__ partial, float* __restrict__ dout,
    float* __restrict__ ws_w, int* __restrict__ ws_idx,
    int* __restrict__ counts, float* __restrict__ probsum,
    int N, int ksplit)
{
  __shared__ float lp[64][EE + 1];
  const int tl = threadIdx.x;
  const int t = blockIdx.x * 64 + tl;
  float maxv = -3.0e38f;
  int arg = 0;
  for (int e = 0; e < EE; ++e) {
    double s = 0.0;
    for (int c = 0; c < ksplit; ++c)
      s += (double)partial[((size_t)c * EE + e) * N + t];
    const float l = (float)s;
    lp[tl][e] = l;
    if (l > maxv) { maxv = l; arg = e; }  // strict > keeps first max (jnp.argmax)
  }
  const double md = (double)maxv;
  double s2 = 0.0;
  for (int e = 0; e < EE; ++e) {
    const double ex = exp((double)lp[tl][e] - md);
    lp[tl][e] = (float)ex;
    s2 += ex;
  }
  const float w = (float)(1.0 / s2);   // max prob = exp(0)/sum
  const float inv = (float)(1.0 / s2);
  for (int e = 0; e < EE; ++e) lp[tl][e] *= inv;  // full softmax row
  dout[t] = w;
  dout[N + t] = (float)arg;
  ws_w[t] = w;
  ws_idx[t] = arg;
  atomicAdd(&counts[arg], 1);
  __syncthreads();
  // deterministic per-block prob sums: thread tl = expert tl
  float ps = 0.f;
  for (int tt = 0; tt < 64; ++tt) ps += lp[tt][tl];
  probsum[(size_t)blockIdx.x * EE + tl] = ps;
}

// ---------------- K2: stats, aux loss, mode ----------------
__global__ __launch_bounds__(64) void sr_stats(
    const float* __restrict__ probsum, const int* __restrict__ counts,
    float* __restrict__ dout, int* __restrict__ header,
    int N, int nblocks, int cap)
{
  const int e = threadIdx.x;
  double ps = 0.0;
  for (int b = 0; b < nblocks; ++b) ps += (double)probsum[(size_t)b * EE + e];
  const int cnt = counts[e];
  dout[2 * N + e] = (float)cnt;  // tokens_per_expert (float)
  __shared__ double mean_s[EE];
  __shared__ int cnt_s[EE];
  mean_s[e] = ps / (double)N;
  cnt_s[e] = cnt;
  __syncthreads();
  if (e == 0) {
    double aux = 0.0;
    int nover = 0, e1 = -1;
    for (int i = 0; i < EE; ++i) {
      aux += ((double)cnt_s[i] / (double)N) * mean_s[i];
      if (cnt_s[i] > cap) { if (nover == 0) e1 = i; ++nover; }
    }
    dout[2 * N + EE] = (float)(aux * (double)EE);  // aux_loss
    header[0] = (nover >= 2) ? 2 : nover;          // mode
    header[1] = e1;
  }
}

// ---------------- K3a: write masked bit-patterns to global scratch ----------------
__global__ __launch_bounds__(256) void sr_maskbits(
    const float* __restrict__ ws_w, const int* __restrict__ ws_idx,
    const int* __restrict__ header, unsigned* __restrict__ mbits, int N)
{
  const int i = blockIdx.x * 256 + threadIdx.x;
  if (i >= N) return;
  unsigned b = 0u;  // sentinel below any positive float's bits
  if (header[0] == 1 && ws_idx[i] == header[1]) b = __float_as_uint(ws_w[i]);
  mbits[i] = b;
}

// ---------------- K3b: exact top-cap selection (mode==1) ----------------
__device__ __forceinline__ int sr_block_sum(int c, int* red, int tid) {
#pragma unroll
  for (int off = 32; off > 0; off >>= 1) c += __shfl_down(c, off, 64);
  __syncthreads();                      // protect red from previous call's readers
  if ((tid & 63) == 0) red[tid >> 6] = c;
  __syncthreads();
  if (tid == 0) {
    int s = 0;
    for (int i = 0; i < 16; ++i) s += red[i];
    red[0] = s;
  }
  __syncthreads();
  return red[0];
}

__global__ __launch_bounds__(1024) void sr_select(
    const unsigned* __restrict__ mbits, int* __restrict__ header, int N, int cap)
{
  __shared__ int red[16];
  const int tid = threadIdx.x;
  const int mode = header[0];
  if (mode != 1) {
    if (tid == 0) { header[2] = 0; header[3] = N; }
    return;
  }
  const int PER = N / 1024;  // 16
  // binary search over f32 bit patterns: largest tau with count(>= tau) >= cap
  unsigned lo = 0u, hi = 0x7f800000u;
  while (hi - lo > 1u) {
    const unsigned mid = lo + ((hi - lo) >> 1);
    int c = 0;
    for (int r = 0; r < PER; ++r) c += (mbits[tid + r * 1024] >= mid);
    const int tot = sr_block_sum(c, red, tid);
    if (tot >= cap) lo = mid; else hi = mid;
  }
  int cge = 0, cgt = 0;
  for (int r = 0; r < PER; ++r) {
    const unsigned v = mbits[tid + r * 1024];
    cge += (v >= lo);
    cgt += (v > lo);
  }
  const int tot_ge = sr_block_sum(cge, red, tid);
  const int tot_gt = sr_block_sum(cgt, red, tid);
  const int quota = cap - tot_gt;  // >= 1
  int idx_thr = N - 1;
  if (tot_ge - tot_gt > quota) {
    // tie at tau: keep the quota lowest-index equals (lax.top_k tie-break)
    int l2 = -1, h2 = N - 1;
    while (h2 - l2 > 1) {
      const int mid = (l2 + h2) >> 1;
      int c = 0;
      for (int r = 0; r < PER; ++r) {
        const int i = tid + r * 1024;
        c += (mbits[i] == lo && i <= mid) ? 1 : 0;
      }
      const int tot = sr_block_sum(c, red, tid);
      if (tot >= quota) h2 = mid; else l2 = mid;
    }
    idx_thr = h2;
  }
  if (tid == 0) { header[2] = (int)lo; header[3] = idx_thr; }
}

// ---------------- K4: apply capacity filter ----------------
__global__ __launch_bounds__(256) void sr_apply(
    const float* __restrict__ ws_w, const int* __restrict__ ws_idx,
    const int* __restrict__ header, float* __restrict__ dout, int N)
{
  const int i = blockIdx.x * 256 + threadIdx.x;
  if (i >= N) return;
  const int mode = header[0];
  const float w = ws_w[i];
  float out = w;
  if (mode == 2) {
    out = 0.f;  // >=2 over-capacity experts: carried zeroing kills everything
  } else if (mode == 1) {
    const int e1 = header[1];
    const unsigned tau = (unsigned)header[2];
    const int ithr = header[3];
    const unsigned b = __float_as_uint(w);
    const bool keep = (ws_idx[i] == e1) && (b > tau || (b == tau && i <= ithr));
    out = keep ? w : 0.f;
  }
  dout[i] = out;
}

// ---------------- launch ----------------
extern "C" void kernel_launch(void* const* d_in, const int* in_sizes, int n_in,
                              void* d_out, int out_size, void* d_ws, size_t ws_size,
                              hipStream_t stream)
{
  const float* x = (const float*)d_in[0];
  const float* wg = (const float*)d_in[1];
  const int N = in_sizes[0] / DD;  // 16384
  float* dout = (float*)d_out;
  float* wsf = (float*)d_ws;

  // ws layout (floats):
  // [ws_w N][ws_idx N][counts 64][probsum (N/64)*64][header 16][mbits N][partial ...]
  float* ws_w = wsf;
  int* ws_idx = (int*)(wsf + N);
  int* counts = (int*)(wsf + 2 * (size_t)N);
  float* probsum = wsf + 2 * (size_t)N + EE;
  const int nblocks_ep = N / 64;
  int* header = (int*)(wsf + 2 * (size_t)N + EE + (size_t)nblocks_ep * EE);
  unsigned* mbits = (unsigned*)(wsf + 2 * (size_t)N + EE + (size_t)nblocks_ep * EE + 16);
  float* partial = wsf + 3 * (size_t)N + EE + (size_t)nblocks_ep * EE + 16;
  const size_t base_floats = 3 * (size_t)N + EE + (size_t)nblocks_ep * EE + 16;

  int ksplit = 8;
  while (ksplit > 1 &&
         (base_floats + (size_t)ksplit * EE * (size_t)N) * sizeof(float) > ws_size)
    ksplit >>= 1;
  const int cap = (int)((double)N * 1.25 / (double)EE);  // 320

  sr_zero<<<1, 64, 0, stream>>>(counts);
  sr_gemm<<<(N / TOKTILE) * ksplit, 256, 0, stream>>>(x, wg, partial, N, ksplit);
  sr_epilogue<<<N / 64, 64, 0, stream>>>(partial, dout, ws_w, ws_idx, counts, probsum, N, ksplit);
  sr_stats<<<1, 64, 0, stream>>>(probsum, counts, dout, header, N, nblocks_ep, cap);
  sr_maskbits<<<(N + 255) / 256, 256, 0, stream>>>(ws_w, ws_idx, header, mbits, N);
  sr_select<<<1, 1024, 0, stream>>>(mbits, header, N, cap);
  sr_apply<<<(N + 255) / 256, 256, 0, stream>>>(ws_w, ws_idx, header, dout, N);
}

// Round 4
// 239.107 us; speedup vs baseline: 1.5206x; 1.5206x over previous
//
#include <hip/hip_runtime.h>
#include <math.h>

#define DD 2048
#define EE 64
#define KQ 32
#define TOKTILE 256

// ---------------- K0: zero the histogram ----------------
__global__ __launch_bounds__(64) void sr_zero(int* __restrict__ counts) {
  counts[threadIdx.x] = 0;
}

// ---------------- K1: gate GEMM, K-split partials ----------------
__global__ __launch_bounds__(256, 2) void sr_gemm(
    const float* __restrict__ x, const float* __restrict__ wg,
    float* __restrict__ partial, int N, int ksplit)
{
  __shared__ float xs[KQ][TOKTILE];  // 32 KB
  __shared__ float wsh[KQ][EE];      // 8 KB
  const int ntiles = N / TOKTILE;
  const int tt = blockIdx.x % ntiles;
  const int kc = blockIdx.x / ntiles;
  const int kblk = DD / ksplit;
  const int nchunk = kblk / KQ;
  const int k0 = kc * kblk;
  const int t0 = tt * TOKTILE;
  const int tid = threadIdx.x;
  const int ti = tid & 31;
  const int tj = tid >> 5;

  float acc[8][8];
#pragma unroll
  for (int r = 0; r < 8; ++r)
#pragma unroll
    for (int c = 0; c < 8; ++c) acc[r][c] = 0.f;

  for (int ch = 0; ch < nchunk; ++ch) {
    const int kb = k0 + ch * KQ;
#pragma unroll
    for (int p = 0; p < 8; ++p) {
      const int row = p * 32 + (tid >> 3);
      const int c4 = (tid & 7) * 4;
      const float4 v = *reinterpret_cast<const float4*>(
          &x[(size_t)(t0 + row) * DD + kb + c4]);
      xs[c4 + 0][row] = v.x;
      xs[c4 + 1][row] = v.y;
      xs[c4 + 2][row] = v.z;
      xs[c4 + 3][row] = v.w;
    }
    {
      const int e = tid >> 2;
      const int kq = (tid & 3) * 8;
      const float4 a = *reinterpret_cast<const float4*>(&wg[(size_t)e * DD + kb + kq]);
      const float4 b = *reinterpret_cast<const float4*>(&wg[(size_t)e * DD + kb + kq + 4]);
      wsh[kq + 0][e] = a.x; wsh[kq + 1][e] = a.y; wsh[kq + 2][e] = a.z; wsh[kq + 3][e] = a.w;
      wsh[kq + 4][e] = b.x; wsh[kq + 5][e] = b.y; wsh[kq + 6][e] = b.z; wsh[kq + 7][e] = b.w;
    }
    __syncthreads();
#pragma unroll 8
    for (int k = 0; k < KQ; ++k) {
      float xv[8], wv[8];
      *reinterpret_cast<float4*>(&xv[0]) = *reinterpret_cast<const float4*>(&xs[k][4 * ti]);
      *reinterpret_cast<float4*>(&xv[4]) = *reinterpret_cast<const float4*>(&xs[k][128 + 4 * ti]);
      *reinterpret_cast<float4*>(&wv[0]) = *reinterpret_cast<const float4*>(&wsh[k][4 * tj]);
      *reinterpret_cast<float4*>(&wv[4]) = *reinterpret_cast<const float4*>(&wsh[k][32 + 4 * tj]);
#pragma unroll
      for (int r = 0; r < 8; ++r)
#pragma unroll
        for (int c = 0; c < 8; ++c) acc[r][c] = fmaf(xv[r], wv[c], acc[r][c]);
    }
    __syncthreads();
  }
#pragma unroll
  for (int c = 0; c < 8; ++c) {
    const int e = (c < 4) ? (4 * tj + c) : (32 + 4 * tj + (c - 4));
#pragma unroll
    for (int h = 0; h < 2; ++h) {
      const int tb = t0 + h * 128 + 4 * ti;
      float4 v = make_float4(acc[h * 4 + 0][c], acc[h * 4 + 1][c],
                             acc[h * 4 + 2][c], acc[h * 4 + 3][c]);
      *reinterpret_cast<float4*>(&partial[((size_t)kc * EE + e) * N + tb]) = v;
    }
  }
}

// ---------------- K2: cross-ksplit reduction -> logits[e][t] ----------------
// f64 sum in fixed c-order: bitwise-identical to the previously-passing path.
__global__ __launch_bounds__(256) void sr_reduce(
    const float* __restrict__ partial, float* __restrict__ logits,
    int N, int ksplit)
{
  const int i = blockIdx.x * 256 + threadIdx.x;  // over EE*N
  if (i >= EE * N) return;
  double s = 0.0;
  for (int c = 0; c < ksplit; ++c)
    s += (double)partial[(size_t)c * EE * N + i];
  logits[i] = (float)s;
}

// ---------------- K3: per-token softmax/argmax epilogue ----------------
__global__ __launch_bounds__(64) void sr_softmax(
    const float* __restrict__ logits, float* __restrict__ dout,
    float* __restrict__ ws_w, int* __restrict__ ws_idx,
    int* __restrict__ counts, float* __restrict__ probsum, int N)
{
  __shared__ float lp[64][EE + 1];
  const int tl = threadIdx.x;
  const int t = blockIdx.x * 64 + tl;
  float l[EE];
  float maxv = -3.0e38f;
  int arg = 0;
#pragma unroll
  for (int e = 0; e < EE; ++e) {
    l[e] = logits[(size_t)e * N + t];  // coalesced across the wave
    if (l[e] > maxv) { maxv = l[e]; arg = e; }  // strict > : first max wins
  }
  float s = 0.f;
#pragma unroll
  for (int e = 0; e < EE; ++e) {
    const float ex = __expf(l[e] - maxv) ;
    lp[tl][e] = ex;
    s += ex;
  }
  // recompute sum accurately (expf ok, but use precise division)
  const float inv = 1.0f / s;
  const float w = inv;  // exp(0)/sum
#pragma unroll
  for (int e = 0; e < EE; ++e) lp[tl][e] *= inv;
  dout[t] = w;
  dout[N + t] = (float)arg;
  ws_w[t] = w;
  ws_idx[t] = arg;
  atomicAdd(&counts[arg], 1);
  __syncthreads();
  float ps = 0.f;
  for (int tt = 0; tt < 64; ++tt) ps += lp[tt][tl];
  probsum[(size_t)blockIdx.x * EE + tl] = ps;
}

// ---------------- K4: stats, aux loss, mode ----------------
__global__ __launch_bounds__(64) void sr_stats(
    const float* __restrict__ probsum, const int* __restrict__ counts,
    float* __restrict__ dout, int* __restrict__ header,
    int N, int nblocks, int cap)
{
  const int e = threadIdx.x;
  double ps = 0.0;
  for (int b = 0; b < nblocks; ++b) ps += (double)probsum[(size_t)b * EE + e];
  const int cnt = counts[e];
  dout[2 * N + e] = (float)cnt;
  __shared__ double mean_s[EE];
  __shared__ int cnt_s[EE];
  mean_s[e] = ps / (double)N;
  cnt_s[e] = cnt;
  __syncthreads();
  if (e == 0) {
    double aux = 0.0;
    int nover = 0, e1 = -1;
    for (int i = 0; i < EE; ++i) {
      aux += ((double)cnt_s[i] / (double)N) * mean_s[i];
      if (cnt_s[i] > cap) { if (nover == 0) e1 = i; ++nover; }
    }
    dout[2 * N + EE] = (float)(aux * (double)EE);
    header[0] = (nover >= 2) ? 2 : nover;
    header[1] = e1;
  }
}

// ---------------- K5a: masked bit-patterns ----------------
__global__ __launch_bounds__(256) void sr_maskbits(
    const float* __restrict__ ws_w, const int* __restrict__ ws_idx,
    const int* __restrict__ header, unsigned* __restrict__ mbits, int N)
{
  const int i = blockIdx.x * 256 + threadIdx.x;
  if (i >= N) return;
  unsigned b = 0u;
  if (header[0] == 1 && ws_idx[i] == header[1]) b = __float_as_uint(ws_w[i]);
  mbits[i] = b;
}

// ---------------- K5b: exact top-cap selection (mode==1) ----------------
__device__ __forceinline__ int sr_block_sum(int c, int* red, int tid) {
#pragma unroll
  for (int off = 32; off > 0; off >>= 1) c += __shfl_down(c, off, 64);
  __syncthreads();
  if ((tid & 63) == 0) red[tid >> 6] = c;
  __syncthreads();
  if (tid == 0) {
    int s = 0;
    for (int i = 0; i < 16; ++i) s += red[i];
    red[0] = s;
  }
  __syncthreads();
  return red[0];
}

__global__ __launch_bounds__(1024) void sr_select(
    const unsigned* __restrict__ mbits, int* __restrict__ header, int N, int cap)
{
  __shared__ int red[16];
  const int tid = threadIdx.x;
  const int mode = header[0];
  if (mode != 1) {
    if (tid == 0) { header[2] = 0; header[3] = N; }
    return;
  }
  const int PER = N / 1024;
  unsigned lo = 0u, hi = 0x7f800000u;
  while (hi - lo > 1u) {
    const unsigned mid = lo + ((hi - lo) >> 1);
    int c = 0;
    for (int r = 0; r < PER; ++r) c += (mbits[tid + r * 1024] >= mid);
    const int tot = sr_block_sum(c, red, tid);
    if (tot >= cap) lo = mid; else hi = mid;
  }
  int cge = 0, cgt = 0;
  for (int r = 0; r < PER; ++r) {
    const unsigned v = mbits[tid + r * 1024];
    cge += (v >= lo);
    cgt += (v > lo);
  }
  const int tot_ge = sr_block_sum(cge, red, tid);
  const int tot_gt = sr_block_sum(cgt, red, tid);
  const int quota = cap - tot_gt;
  int idx_thr = N - 1;
  if (tot_ge - tot_gt > quota) {
    int l2 = -1, h2 = N - 1;
    while (h2 - l2 > 1) {
      const int mid = (l2 + h2) >> 1;
      int c = 0;
      for (int r = 0; r < PER; ++r) {
        const int i = tid + r * 1024;
        c += (mbits[i] == lo && i <= mid) ? 1 : 0;
      }
      const int tot = sr_block_sum(c, red, tid);
      if (tot >= quota) h2 = mid; else l2 = mid;
    }
    idx_thr = h2;
  }
  if (tid == 0) { header[2] = (int)lo; header[3] = idx_thr; }
}

// ---------------- K6: apply capacity filter ----------------
__global__ __launch_bounds__(256) void sr_apply(
    const float* __restrict__ ws_w, const int* __restrict__ ws_idx,
    const int* __restrict__ header, float* __restrict__ dout, int N)
{
  const int i = blockIdx.x * 256 + threadIdx.x;
  if (i >= N) return;
  const int mode = header[0];
  const float w = ws_w[i];
  float out = w;
  if (mode == 2) {
    out = 0.f;
  } else if (mode == 1) {
    const int e1 = header[1];
    const unsigned tau = (unsigned)header[2];
    const int ithr = header[3];
    const unsigned b = __float_as_uint(w);
    const bool keep = (ws_idx[i] == e1) && (b > tau || (b == tau && i <= ithr));
    out = keep ? w : 0.f;
  }
  dout[i] = out;
}

// ---------------- launch ----------------
extern "C" void kernel_launch(void* const* d_in, const int* in_sizes, int n_in,
                              void* d_out, int out_size, void* d_ws, size_t ws_size,
                              hipStream_t stream)
{
  const float* x = (const float*)d_in[0];
  const float* wg = (const float*)d_in[1];
  const int N = in_sizes[0] / DD;  // 16384
  float* dout = (float*)d_out;
  float* wsf = (float*)d_ws;

  // ws layout (floats):
  // [ws_w N][ws_idx N][counts 64][probsum (N/64)*64][header 16][mbits N][logits EE*N][partial ...]
  float* ws_w = wsf;
  int* ws_idx = (int*)(wsf + N);
  int* counts = (int*)(wsf + 2 * (size_t)N);
  float* probsum = wsf + 2 * (size_t)N + EE;
  const int nblocks_ep = N / 64;
  int* header = (int*)(wsf + 2 * (size_t)N + EE + (size_t)nblocks_ep * EE);
  unsigned* mbits = (unsigned*)(wsf + 2 * (size_t)N + EE + (size_t)nblocks_ep * EE + 16);
  float* logits = wsf + 3 * (size_t)N + EE + (size_t)nblocks_ep * EE + 16;
  float* partial = logits + (size_t)EE * N;
  const size_t base_floats = 3 * (size_t)N + EE + (size_t)nblocks_ep * EE + 16 + (size_t)EE * N;

  int ksplit = 8;
  while (ksplit > 1 &&
         (base_floats + (size_t)ksplit * EE * (size_t)N) * sizeof(float) > ws_size)
    ksplit >>= 1;
  const int cap = (int)((double)N * 1.25 / (double)EE);  // 320

  sr_zero<<<1, 64, 0, stream>>>(counts);
  sr_gemm<<<(N / TOKTILE) * ksplit, 256, 0, stream>>>(x, wg, partial, N, ksplit);
  sr_reduce<<<(EE * N + 255) / 256, 256, 0, stream>>>(partial, logits, N, ksplit);
  sr_softmax<<<N / 64, 64, 0, stream>>>(logits, dout, ws_w, ws_idx, counts, probsum, N);
  sr_stats<<<1, 64, 0, stream>>>(probsum, counts, dout, header, N, nblocks_ep, cap);
  sr_maskbits<<<(N + 255) / 256, 256, 0, stream>>>(ws_w, ws_idx, header, mbits, N);
  sr_select<<<1, 1024, 0, stream>>>(mbits, header, N, cap);
  sr_apply<<<(N + 255) / 256, 256, 0, stream>>>(ws_w, ws_idx, header, dout, N);
}

// Round 5
// 198.399 us; speedup vs baseline: 1.8326x; 1.2052x over previous
//
#include <hip/hip_runtime.h>
#include <math.h>

#define DD 2048
#define EE 64
#define KQ 32
#define TOKTILE 128

// ---------------- K1: gate GEMM, K-split partials ----------------
// Tile: 128 tokens x 64 experts x 256 k per block. Thread tile 4 tok x 8 exp.
// xs is XOR-swizzled (t ^ 8*((k>>2)&3)) so transpose-staging writes are 2-way
// (free) instead of 8-way bank-conflicted.
__global__ __launch_bounds__(256, 4) void sr_gemm(
    const float* __restrict__ x, const float* __restrict__ wg,
    float* __restrict__ partial, int N, int ksplit)
{
  __shared__ float xs[KQ][TOKTILE];  // 16 KB, swizzled
  __shared__ float wsh[KQ][EE];      // 8 KB
  const int ntiles = N / TOKTILE;
  const int tt = blockIdx.x % ntiles;
  const int kc = blockIdx.x / ntiles;
  const int kblk = DD / ksplit;
  const int nchunk = kblk / KQ;
  const int k0 = kc * kblk;
  const int t0 = tt * TOKTILE;
  const int tid = threadIdx.x;
  const int ti = tid & 31;   // token quad: tokens 4*ti .. 4*ti+3
  const int tj = tid >> 5;   // expert octet: experts 8*tj .. 8*tj+7

  float acc[4][8];
#pragma unroll
  for (int r = 0; r < 4; ++r)
#pragma unroll
    for (int c = 0; c < 8; ++c) acc[r][c] = 0.f;

  // staging indices (x): 4 rounds cover 128 rows x 32 k
  const int srowbase = tid >> 3;          // 0..7 within each round
  const int c4 = (tid & 7) * 4;           // k quad base
  const int swz = 8 * (tid & 3);          // == 8 * (((c4+j)>>2) & 3)

  for (int ch = 0; ch < nchunk; ++ch) {
    const int kb = k0 + ch * KQ;
#pragma unroll
    for (int p = 0; p < 4; ++p) {
      const int row = p * 32 + srowbase;
      const float4 v = *reinterpret_cast<const float4*>(
          &x[(size_t)(t0 + row) * DD + kb + c4]);
      const int srow = row ^ swz;         // 2-way bank spread on writes
      xs[c4 + 0][srow] = v.x;
      xs[c4 + 1][srow] = v.y;
      xs[c4 + 2][srow] = v.z;
      xs[c4 + 3][srow] = v.w;
    }
    {
      const int e = tid >> 2;
      const int kq = (tid & 3) * 8;
      const float4 a = *reinterpret_cast<const float4*>(&wg[(size_t)e * DD + kb + kq]);
      const float4 b = *reinterpret_cast<const float4*>(&wg[(size_t)e * DD + kb + kq + 4]);
      wsh[kq + 0][e] = a.x; wsh[kq + 1][e] = a.y; wsh[kq + 2][e] = a.z; wsh[kq + 3][e] = a.w;
      wsh[kq + 4][e] = b.x; wsh[kq + 5][e] = b.y; wsh[kq + 6][e] = b.z; wsh[kq + 7][e] = b.w;
    }
    __syncthreads();
#pragma unroll 8
    for (int k = 0; k < KQ; ++k) {
      const int sk = 8 * ((k >> 2) & 3);
      float xv[4], wv[8];
      *reinterpret_cast<float4*>(&xv[0]) =
          *reinterpret_cast<const float4*>(&xs[k][(4 * ti) ^ sk]);
      *reinterpret_cast<float4*>(&wv[0]) = *reinterpret_cast<const float4*>(&wsh[k][8 * tj]);
      *reinterpret_cast<float4*>(&wv[4]) = *reinterpret_cast<const float4*>(&wsh[k][8 * tj + 4]);
#pragma unroll
      for (int r = 0; r < 4; ++r)
#pragma unroll
        for (int c = 0; c < 8; ++c) acc[r][c] = fmaf(xv[r], wv[c], acc[r][c]);
    }
    __syncthreads();
  }
  // partial[kc][e][t]: float4 over tokens, coalesced
#pragma unroll
  for (int c = 0; c < 8; ++c) {
    const int e = 8 * tj + c;
    const float4 v = make_float4(acc[0][c], acc[1][c], acc[2][c], acc[3][c]);
    *reinterpret_cast<float4*>(&partial[((size_t)kc * EE + e) * N + t0 + 4 * ti]) = v;
  }
}

// ---------------- K2: cross-ksplit reduction -> logits[e][t] (+zero counts) ----
// f64 sum in fixed c-order: bitwise-identical to the passing path.
__global__ __launch_bounds__(256) void sr_reduce(
    const float* __restrict__ partial, float* __restrict__ logits,
    int* __restrict__ counts, int N, int ksplit)
{
  if (blockIdx.x == 0 && threadIdx.x < EE) counts[threadIdx.x] = 0;
  const int i4 = blockIdx.x * 256 + threadIdx.x;   // over EE*N/4
  const size_t base = (size_t)i4 * 4;
  if (base >= (size_t)EE * N) return;
  const size_t cs = (size_t)EE * N;
  double s0 = 0.0, s1 = 0.0, s2 = 0.0, s3 = 0.0;
  for (int c = 0; c < ksplit; ++c) {
    const float4 v = *reinterpret_cast<const float4*>(&partial[c * cs + base]);
    s0 += (double)v.x; s1 += (double)v.y; s2 += (double)v.z; s3 += (double)v.w;
  }
  *reinterpret_cast<float4*>(&logits[base]) =
      make_float4((float)s0, (float)s1, (float)s2, (float)s3);
}

// ---------------- K3: per-token softmax/argmax epilogue ----------------
__global__ __launch_bounds__(64) void sr_softmax(
    const float* __restrict__ logits, float* __restrict__ dout,
    float* __restrict__ ws_w, int* __restrict__ ws_idx,
    int* __restrict__ counts, float* __restrict__ probsum, int N)
{
  __shared__ float lp[64][EE + 1];
  const int tl = threadIdx.x;
  const int t = blockIdx.x * 64 + tl;
  float l[EE];
  float maxv = -3.0e38f;
  int arg = 0;
#pragma unroll
  for (int e = 0; e < EE; ++e) {
    l[e] = logits[(size_t)e * N + t];  // coalesced across the wave
    if (l[e] > maxv) { maxv = l[e]; arg = e; }  // strict > : first max wins
  }
  float s = 0.f;
#pragma unroll
  for (int e = 0; e < EE; ++e) {
    const float ex = __expf(l[e] - maxv);
    lp[tl][e] = ex;
    s += ex;
  }
  const float inv = 1.0f / s;
  const float w = inv;  // exp(0)/sum
#pragma unroll
  for (int e = 0; e < EE; ++e) lp[tl][e] *= inv;
  dout[t] = w;
  dout[N + t] = (float)arg;
  ws_w[t] = w;
  ws_idx[t] = arg;
  atomicAdd(&counts[arg], 1);
  __syncthreads();
  float ps = 0.f;
  for (int tt = 0; tt < 64; ++tt) ps += lp[tt][tl];
  probsum[(size_t)blockIdx.x * EE + tl] = ps;
}

// ---------------- K4: stats, aux loss, mode ----------------
__global__ __launch_bounds__(64) void sr_stats(
    const float* __restrict__ probsum, const int* __restrict__ counts,
    float* __restrict__ dout, int* __restrict__ header,
    int N, int nblocks, int cap)
{
  const int e = threadIdx.x;
  double ps = 0.0;
  for (int b = 0; b < nblocks; ++b) ps += (double)probsum[(size_t)b * EE + e];
  const int cnt = counts[e];
  dout[2 * N + e] = (float)cnt;
  __shared__ double mean_s[EE];
  __shared__ int cnt_s[EE];
  mean_s[e] = ps / (double)N;
  cnt_s[e] = cnt;
  __syncthreads();
  if (e == 0) {
    double aux = 0.0;
    int nover = 0, e1 = -1;
    for (int i = 0; i < EE; ++i) {
      aux += ((double)cnt_s[i] / (double)N) * mean_s[i];
      if (cnt_s[i] > cap) { if (nover == 0) e1 = i; ++nover; }
    }
    dout[2 * N + EE] = (float)(aux * (double)EE);
    header[0] = (nover >= 2) ? 2 : nover;
    header[1] = e1;
  }
}

// ---------------- K5: exact top-cap selection (mode==1), register-cached ----
__device__ __forceinline__ int sr_block_sum(int c, int* red, int tid) {
#pragma unroll
  for (int off = 32; off > 0; off >>= 1) c += __shfl_down(c, off, 64);
  __syncthreads();
  if ((tid & 63) == 0) red[tid >> 6] = c;
  __syncthreads();
  if (tid == 0) {
    int s = 0;
    for (int i = 0; i < 16; ++i) s += red[i];
    red[0] = s;
  }
  __syncthreads();
  return red[0];
}

__global__ __launch_bounds__(1024) void sr_select(
    const float* __restrict__ ws_w, const int* __restrict__ ws_idx,
    int* __restrict__ header, int N, int cap)
{
  __shared__ int red[16];
  const int tid = threadIdx.x;
  const int mode = header[0];
  if (mode != 1) {
    if (tid == 0) { header[2] = 0; header[3] = N; }
    return;
  }
  const int e1 = header[1];
  unsigned mb[16];  // PER = N/1024 = 16, cached in VGPRs
  const int PER = N / 1024;
  for (int r = 0; r < 16; ++r) {
    unsigned b = 0u;
    if (r < PER) {
      const int i = tid + r * 1024;
      if (ws_idx[i] == e1) b = __float_as_uint(ws_w[i]);
    }
    mb[r] = b;
  }
  // binary search over f32 bit patterns: largest tau with count(>= tau) >= cap
  unsigned lo = 0u, hi = 0x7f800000u;
  while (hi - lo > 1u) {
    const unsigned mid = lo + ((hi - lo) >> 1);
    int c = 0;
#pragma unroll
    for (int r = 0; r < 16; ++r) c += (mb[r] >= mid);
    const int tot = sr_block_sum(c, red, tid);
    if (tot >= cap) lo = mid; else hi = mid;
  }
  int cge = 0, cgt = 0;
#pragma unroll
  for (int r = 0; r < 16; ++r) {
    cge += (mb[r] >= lo);
    cgt += (mb[r] > lo);
  }
  const int tot_ge = sr_block_sum(cge, red, tid);
  const int tot_gt = sr_block_sum(cgt, red, tid);
  const int quota = cap - tot_gt;
  int idx_thr = N - 1;
  if (tot_ge - tot_gt > quota) {
    // tie at tau: keep the quota lowest-index equals (lax.top_k tie-break)
    int l2 = -1, h2 = N - 1;
    while (h2 - l2 > 1) {
      const int mid = (l2 + h2) >> 1;
      int c = 0;
#pragma unroll
      for (int r = 0; r < 16; ++r) {
        const int i = tid + r * 1024;
        c += (mb[r] == lo && mb[r] != 0u && i <= mid) ? 1 : 0;
      }
      const int tot = sr_block_sum(c, red, tid);
      if (tot >= quota) h2 = mid; else l2 = mid;
    }
    idx_thr = h2;
  }
  if (tid == 0) { header[2] = (int)lo; header[3] = idx_thr; }
}

// ---------------- K6: apply capacity filter ----------------
__global__ __launch_bounds__(256) void sr_apply(
    const float* __restrict__ ws_w, const int* __restrict__ ws_idx,
    const int* __restrict__ header, float* __restrict__ dout, int N)
{
  const int i = blockIdx.x * 256 + threadIdx.x;
  if (i >= N) return;
  const int mode = header[0];
  const float w = ws_w[i];
  float out = w;
  if (mode == 2) {
    out = 0.f;
  } else if (mode == 1) {
    const int e1 = header[1];
    const unsigned tau = (unsigned)header[2];
    const int ithr = header[3];
    const unsigned b = __float_as_uint(w);
    const bool keep = (ws_idx[i] == e1) && (b > tau || (b == tau && i <= ithr));
    out = keep ? w : 0.f;
  }
  dout[i] = out;
}

// ---------------- launch ----------------
extern "C" void kernel_launch(void* const* d_in, const int* in_sizes, int n_in,
                              void* d_out, int out_size, void* d_ws, size_t ws_size,
                              hipStream_t stream)
{
  const float* x = (const float*)d_in[0];
  const float* wg = (const float*)d_in[1];
  const int N = in_sizes[0] / DD;  // 16384
  float* dout = (float*)d_out;
  float* wsf = (float*)d_ws;

  // ws layout (floats):
  // [ws_w N][ws_idx N][counts 64][probsum (N/64)*64][header 16][logits EE*N][partial ...]
  float* ws_w = wsf;
  int* ws_idx = (int*)(wsf + N);
  int* counts = (int*)(wsf + 2 * (size_t)N);
  float* probsum = wsf + 2 * (size_t)N + EE;
  const int nblocks_ep = N / 64;
  int* header = (int*)(wsf + 2 * (size_t)N + EE + (size_t)nblocks_ep * EE);
  float* logits = wsf + 2 * (size_t)N + EE + (size_t)nblocks_ep * EE + 16;
  float* partial = logits + (size_t)EE * N;
  const size_t base_floats = 2 * (size_t)N + EE + (size_t)nblocks_ep * EE + 16 + (size_t)EE * N;

  int ksplit = 8;
  while (ksplit > 1 &&
         (base_floats + (size_t)ksplit * EE * (size_t)N) * sizeof(float) > ws_size)
    ksplit >>= 1;
  const int cap = (int)((double)N * 1.25 / (double)EE);  // 320

  sr_gemm<<<(N / TOKTILE) * ksplit, 256, 0, stream>>>(x, wg, partial, N, ksplit);
  sr_reduce<<<(EE * N / 4 + 255) / 256, 256, 0, stream>>>(partial, logits, counts, N, ksplit);
  sr_softmax<<<N / 64, 64, 0, stream>>>(logits, dout, ws_w, ws_idx, counts, probsum, N);
  sr_stats<<<1, 64, 0, stream>>>(probsum, counts, dout, header, N, nblocks_ep, cap);
  sr_select<<<1, 1024, 0, stream>>>(ws_w, ws_idx, header, N, cap);
  sr_apply<<<(N + 255) / 256, 256, 0, stream>>>(ws_w, ws_idx, header, dout, N);
}

// Round 6
// 156.240 us; speedup vs baseline: 2.3271x; 1.2698x over previous
//
#include <hip/hip_runtime.h>
#include <math.h>

#define DD 2048
#define EE 64
#define KQ 32
#define TOKTILE 256

// ---------------- K1: gate GEMM, K-split partials ----------------
// 512 thr = 8 waves; wave w owns experts 8w..8w+7 (wave-uniform -> w operands
// come from SGPRs via scalar loads; zero LDS reads for w). Thread: 4 tok x 8 exp.
// Per k per wave: 1 ds_read_b128 (256 distinct tokens, conflict-free) + 32 FMA.
__global__ __launch_bounds__(512, 4) void sr_gemm(
    const float* __restrict__ x, const float* __restrict__ wg,
    float* __restrict__ partial, int N, int ksplit)
{
  __shared__ float xs[KQ][TOKTILE];  // 32 KB, swizzled
  const int ntiles = N / TOKTILE;
  const int tt = blockIdx.x % ntiles;
  const int kc = blockIdx.x / ntiles;
  const int kblk = DD / ksplit;
  const int nchunk = kblk / KQ;
  const int k0 = kc * kblk;
  const int t0 = tt * TOKTILE;
  const int tid = threadIdx.x;
  const int ti = tid & 63;                                  // token quad 4ti..4ti+3
  const int wv = __builtin_amdgcn_readfirstlane(tid >> 6);  // wave id, uniform -> SGPR

  float acc[4][8];
#pragma unroll
  for (int r = 0; r < 4; ++r)
#pragma unroll
    for (int c = 0; c < 8; ++c) acc[r][c] = 0.f;

  // staging: 4 rounds x 64 rows x 32 k, XOR-swizzled (t ^ 8*((k>>2)&3))
  const int srowbase = tid >> 3;   // 0..63
  const int c4 = (tid & 7) * 4;
  const int swz = 8 * (tid & 3);   // == 8*(((c4+j)>>2)&3)

  for (int ch = 0; ch < nchunk; ++ch) {
    const int kb = k0 + ch * KQ;
#pragma unroll
    for (int p = 0; p < 4; ++p) {
      const int row = p * 64 + srowbase;
      const float4 v = *reinterpret_cast<const float4*>(
          &x[(size_t)(t0 + row) * DD + kb + c4]);
      const int srow = row ^ swz;
      xs[c4 + 0][srow] = v.x;
      xs[c4 + 1][srow] = v.y;
      xs[c4 + 2][srow] = v.z;
      xs[c4 + 3][srow] = v.w;
    }
    __syncthreads();
#pragma unroll
    for (int sub = 0; sub < 8; ++sub) {
      // w[8wv+c][kb+4sub .. +3] : uniform address -> s_load_dwordx4 into SGPRs
      float4 wq[8];
#pragma unroll
      for (int c = 0; c < 8; ++c)
        wq[c] = *reinterpret_cast<const float4*>(
            &wg[(size_t)(8 * wv + c) * DD + kb + 4 * sub]);
      const int sk = 8 * (sub & 3);  // k>>2 == sub within this group
#pragma unroll
      for (int kk = 0; kk < 4; ++kk) {
        const int k = 4 * sub + kk;
        float xv[4];
        *reinterpret_cast<float4*>(&xv[0]) =
            *reinterpret_cast<const float4*>(&xs[k][(4 * ti) ^ sk]);
#pragma unroll
        for (int r = 0; r < 4; ++r)
#pragma unroll
          for (int c = 0; c < 8; ++c)
            acc[r][c] = fmaf(xv[r], reinterpret_cast<const float*>(&wq[c])[kk],
                             acc[r][c]);
      }
    }
    __syncthreads();
  }
  // partial[kc][e][t]: per wave 64 lanes x 16B = 1KB contiguous
#pragma unroll
  for (int c = 0; c < 8; ++c) {
    const int e = 8 * wv + c;
    const float4 v = make_float4(acc[0][c], acc[1][c], acc[2][c], acc[3][c]);
    *reinterpret_cast<float4*>(&partial[((size_t)kc * EE + e) * N + t0 + 4 * ti]) = v;
  }
}

// ---------------- K2: cross-ksplit reduction -> logits[e][t] (+zero counts) ----
// f64 sum in fixed c-order: bitwise-identical to the passing path.
__global__ __launch_bounds__(256) void sr_reduce(
    const float* __restrict__ partial, float* __restrict__ logits,
    int* __restrict__ counts, int N, int ksplit)
{
  if (blockIdx.x == 0 && threadIdx.x < EE) counts[threadIdx.x] = 0;
  const int i4 = blockIdx.x * 256 + threadIdx.x;   // over EE*N/4
  const size_t base = (size_t)i4 * 4;
  if (base >= (size_t)EE * N) return;
  const size_t cs = (size_t)EE * N;
  double s0 = 0.0, s1 = 0.0, s2 = 0.0, s3 = 0.0;
  for (int c = 0; c < ksplit; ++c) {
    const float4 v = *reinterpret_cast<const float4*>(&partial[c * cs + base]);
    s0 += (double)v.x; s1 += (double)v.y; s2 += (double)v.z; s3 += (double)v.w;
  }
  *reinterpret_cast<float4*>(&logits[base]) =
      make_float4((float)s0, (float)s1, (float)s2, (float)s3);
}

// ---------------- K3: per-token softmax/argmax (128 tok / 256 thr blocks) ----
__global__ __launch_bounds__(256) void sr_softmax(
    const float* __restrict__ logits, float* __restrict__ dout,
    float* __restrict__ ws_w, int* __restrict__ ws_idx,
    int* __restrict__ counts, float* __restrict__ probsum, int N)
{
  __shared__ float lp[128][EE + 1];
  __shared__ float psq[4][EE];
  const int tid = threadIdx.x;
  const int t0 = blockIdx.x * 128;
  if (tid < 128) {
    const int t = t0 + tid;
    float l[EE];
    float maxv = -3.0e38f;
    int arg = 0;
#pragma unroll
    for (int e = 0; e < EE; ++e) {
      l[e] = logits[(size_t)e * N + t];
      if (l[e] > maxv) { maxv = l[e]; arg = e; }  // strict > : first max wins
    }
    float s = 0.f;
#pragma unroll
    for (int e = 0; e < EE; ++e) {
      const float ex = __expf(l[e] - maxv);
      lp[tid][e] = ex;
      s += ex;
    }
    const float inv = 1.0f / s;
    const float w = inv;  // exp(0)/sum
#pragma unroll
    for (int e = 0; e < EE; ++e) lp[tid][e] *= inv;
    dout[t] = w;
    dout[N + t] = (float)arg;
    ws_w[t] = w;
    ws_idx[t] = arg;
    atomicAdd(&counts[arg], 1);
  }
  __syncthreads();
  const int e = tid & 63, q = tid >> 6;
  float ps = 0.f;
  for (int r = 0; r < 32; ++r) ps += lp[q * 32 + r][e];
  psq[q][e] = ps;
  __syncthreads();
  if (tid < 64) {
    const float tot = ((psq[0][tid] + psq[1][tid]) + psq[2][tid]) + psq[3][tid];
    probsum[(size_t)blockIdx.x * EE + tid] = tot;
  }
}

// ---------------- K4: stats, aux loss, mode ----------------
__global__ __launch_bounds__(256) void sr_stats(
    const float* __restrict__ probsum, const int* __restrict__ counts,
    float* __restrict__ dout, int* __restrict__ header,
    int N, int nblocks, int cap)
{
  __shared__ double dq[4][EE];
  __shared__ double mean_s[EE];
  __shared__ int cnt_s[EE];
  const int tid = threadIdx.x;
  const int e = tid & 63, q = tid >> 6;
  const int per = nblocks / 4;
  double ps = 0.0;
  for (int b = q * per; b < (q + 1) * per; ++b)
    ps += (double)probsum[(size_t)b * EE + e];
  dq[q][e] = ps;
  __syncthreads();
  if (tid < 64) {
    const double tot = ((dq[0][tid] + dq[1][tid]) + dq[2][tid]) + dq[3][tid];
    const int cnt = counts[tid];
    dout[2 * N + tid] = (float)cnt;
    mean_s[tid] = tot / (double)N;
    cnt_s[tid] = cnt;
  }
  __syncthreads();
  if (tid == 0) {
    double aux = 0.0;
    int nover = 0, e1 = -1;
    for (int i = 0; i < EE; ++i) {
      aux += ((double)cnt_s[i] / (double)N) * mean_s[i];
      if (cnt_s[i] > cap) { if (nover == 0) e1 = i; ++nover; }
    }
    dout[2 * N + EE] = (float)(aux * (double)EE);
    header[0] = (nover >= 2) ? 2 : nover;
    header[1] = e1;
  }
}

// ---------------- K5: exact top-cap selection (mode==1) ----------------
// 1-barrier block sum: wave shfl reduce + parity-double-buffered LDS combine.
__device__ __forceinline__ int sr_bsum(int c, int red[][16], int pc, int tid) {
#pragma unroll
  for (int off = 32; off > 0; off >>= 1) c += __shfl_down(c, off, 64);
  if ((tid & 63) == 0) red[pc & 1][tid >> 6] = c;
  __syncthreads();
  int s = 0;
#pragma unroll
  for (int i = 0; i < 16; ++i) s += red[pc & 1][i];
  return s;
}

__global__ __launch_bounds__(1024) void sr_select(
    const float* __restrict__ ws_w, const int* __restrict__ ws_idx,
    int* __restrict__ header, int N, int cap)
{
  __shared__ int red[2][16];
  const int tid = threadIdx.x;
  const int mode = header[0];
  if (mode != 1) {
    if (tid == 0) { header[2] = 0; header[3] = N; }
    return;
  }
  const int e1 = header[1];
  unsigned mb[16];  // PER = N/1024 = 16, cached in VGPRs
  const int PER = N / 1024;
  for (int r = 0; r < 16; ++r) {
    unsigned b = 0u;
    if (r < PER) {
      const int i = tid + r * 1024;
      if (ws_idx[i] == e1) b = __float_as_uint(ws_w[i]);
    }
    mb[r] = b;
  }
  int pc = 0;
  // w = 1/softmax_sum in [1/64, 1): search bits in [0x3C000000, 0x3F800000)
  unsigned lo = 0x3C000000u, hi = 0x3F800000u;
  while (hi - lo > 1u) {
    const unsigned mid = lo + ((hi - lo) >> 1);
    int c = 0;
#pragma unroll
    for (int r = 0; r < 16; ++r) c += (mb[r] >= mid);
    const int tot = sr_bsum(c, red, pc++, tid);
    if (tot >= cap) lo = mid; else hi = mid;
  }
  int cge = 0, cgt = 0;
#pragma unroll
  for (int r = 0; r < 16; ++r) {
    cge += (mb[r] >= lo);
    cgt += (mb[r] > lo);
  }
  const int tot_ge = sr_bsum(cge, red, pc++, tid);
  const int tot_gt = sr_bsum(cgt, red, pc++, tid);
  const int quota = cap - tot_gt;
  int idx_thr = N - 1;
  if (tot_ge - tot_gt > quota) {
    // tie at tau: keep the quota lowest-index equals (lax.top_k tie-break)
    int l2 = -1, h2 = N - 1;
    while (h2 - l2 > 1) {
      const int mid = (l2 + h2) >> 1;
      int c = 0;
#pragma unroll
      for (int r = 0; r < 16; ++r) {
        const int i = tid + r * 1024;
        c += (mb[r] == lo && mb[r] != 0u && i <= mid) ? 1 : 0;
      }
      const int tot = sr_bsum(c, red, pc++, tid);
      if (tot >= quota) h2 = mid; else l2 = mid;
    }
    idx_thr = h2;
  }
  if (tid == 0) { header[2] = (int)lo; header[3] = idx_thr; }
}

// ---------------- K6: apply capacity filter ----------------
__global__ __launch_bounds__(256) void sr_apply(
    const float* __restrict__ ws_w, const int* __restrict__ ws_idx,
    const int* __restrict__ header, float* __restrict__ dout, int N)
{
  const int i = blockIdx.x * 256 + threadIdx.x;
  if (i >= N) return;
  const int mode = header[0];
  const float w = ws_w[i];
  float out = w;
  if (mode == 2) {
    out = 0.f;
  } else if (mode == 1) {
    const int e1 = header[1];
    const unsigned tau = (unsigned)header[2];
    const int ithr = header[3];
    const unsigned b = __float_as_uint(w);
    const bool keep = (ws_idx[i] == e1) && (b > tau || (b == tau && i <= ithr));
    out = keep ? w : 0.f;
  }
  dout[i] = out;
}

// ---------------- launch ----------------
extern "C" void kernel_launch(void* const* d_in, const int* in_sizes, int n_in,
                              void* d_out, int out_size, void* d_ws, size_t ws_size,
                              hipStream_t stream)
{
  const float* x = (const float*)d_in[0];
  const float* wg = (const float*)d_in[1];
  const int N = in_sizes[0] / DD;  // 16384
  float* dout = (float*)d_out;
  float* wsf = (float*)d_ws;

  // ws layout (floats):
  // [ws_w N][ws_idx N][counts 64][probsum (N/128)*64][header 16][logits EE*N][partial ...]
  float* ws_w = wsf;
  int* ws_idx = (int*)(wsf + N);
  int* counts = (int*)(wsf + 2 * (size_t)N);
  float* probsum = wsf + 2 * (size_t)N + EE;
  const int nblocks_sm = N / 128;
  int* header = (int*)(wsf + 2 * (size_t)N + EE + (size_t)nblocks_sm * EE);
  float* logits = wsf + 2 * (size_t)N + EE + (size_t)nblocks_sm * EE + 16;
  float* partial = logits + (size_t)EE * N;
  const size_t base_floats = 2 * (size_t)N + EE + (size_t)nblocks_sm * EE + 16 + (size_t)EE * N;

  int ksplit = 8;
  while (ksplit > 1 &&
         (base_floats + (size_t)ksplit * EE * (size_t)N) * sizeof(float) > ws_size)
    ksplit >>= 1;
  const int cap = (int)((double)N * 1.25 / (double)EE);  // 320

  sr_gemm<<<(N / TOKTILE) * ksplit, 512, 0, stream>>>(x, wg, partial, N, ksplit);
  sr_reduce<<<(EE * N / 4 + 255) / 256, 256, 0, stream>>>(partial, logits, counts, N, ksplit);
  sr_softmax<<<N / 128, 256, 0, stream>>>(logits, dout, ws_w, ws_idx, counts, probsum, N);
  sr_stats<<<1, 256, 0, stream>>>(probsum, counts, dout, header, N, nblocks_sm, cap);
  sr_select<<<1, 1024, 0, stream>>>(ws_w, ws_idx, header, N, cap);
  sr_apply<<<(N + 255) / 256, 256, 0, stream>>>(ws_w, ws_idx, header, dout, N);
}